// Round 3
// baseline (237.425 us; speedup 1.0000x reference)
//
#include <hip/hip_runtime.h>
#include <math.h>

#define T_DIM 4096
#define B_DIM 8
#define C_DIM 1024
#define H_DIM 16
#define K_DIM 31
#define PAD_L 30
#define TILE_T 32
#define WIN 62                 // TILE_T + K_DIM - 1
#define BLOCK 256
#define RING_ROWS 64           // mod-64 row ring in LDS
#define TPB 8                  // t-tiles per persistent block

typedef __attribute__((ext_vector_type(4))) float f32x4;

// Async global->LDS DMA: 64 lanes x 16 B = one full 1 KB ring row per instr.
__device__ __forceinline__ void stage16(const float* g, float* l) {
    __builtin_amdgcn_global_load_lds(
        (const __attribute__((address_space(1))) void*)g,
        (__attribute__((address_space(3))) void*)l,
        16, 0, 0);
}

// Window row J of tile at t0 lives in ring slot (t0 + J - 30) & 63.
// TPAR = t0 & 63 (only 0 or 32) => slot is a compile-time immediate.
// Template recursion: every acc/taps index provably constant (R4 scratch lesson).
// acc[i] is INITIALIZED (not accumulated) at J == i via taps[0]*x: no zero-init pass.

template <int TPAR, int J>
__device__ __forceinline__ void conv_a(const float* col,
                                       const float (&taps)[K_DIM],
                                       float (&acc)[TILE_T]) {
    if constexpr (J < 30) {
        const float xj = col[((TPAR + J + 34) & 63) * BLOCK];
        #pragma unroll
        for (int i = 0; i <= J; ++i) {
            if (i == J) acc[i] = taps[0] * xj;
            else        acc[i] = fmaf(taps[J - i], xj, acc[i]);
        }
        conv_a<TPAR, J + 1>(col, taps, acc);
    }
}

template <int TPAR, int J>
__device__ __forceinline__ void conv_b(const float* col,
                                       const float (&taps)[K_DIM],
                                       float (&acc)[TILE_T],
                                       float* po, long stride) {
    if constexpr (J < WIN) {
        const float xj = col[((TPAR + J + 34) & 63) * BLOCK];
        constexpr int ilo = J - 30;
        constexpr int ihi = (J < TILE_T - 1) ? J : TILE_T - 1;
        #pragma unroll
        for (int i = ilo; i <= ihi; ++i) {
            if (i == J) acc[i] = taps[0] * xj;
            else        acc[i] = fmaf(taps[J - i], xj, acc[i]);
        }
        // acc[J-30] is complete here (last tap k=0 applied at J = i+30... i=J-30).
        __builtin_nontemporal_store(acc[J - 30], po + (long)(J - 30) * stride);
        conv_b<TPAR, J + 1>(col, taps, acc, po, stride);
    }
}

// One tile iteration. Phase A reads the 30 oldest rows (slots about to be
// recycled), barrier, THEN issue the async stage of the next 32 rows into
// those slots, then phase B computes on rows staged last iteration while the
// DMA flies. Barrier #2's vmcnt(0) lands ~1100cy after issue: latency hidden.
template <int TPAR>
__device__ __forceinline__ void iter_body(
    const float* __restrict__ x, float* __restrict__ out,
    const float* col, float* lds0,
    const float (&taps)[K_DIM],
    long t0, int wv, int lane, int cc0, int tid, bool stage_next)
{
    const long stride = (long)B_DIM * C_DIM;
    float acc[TILE_T];

    conv_a<TPAR, 0>(col, taps, acc);

    __syncthreads();                       // all waves done reading old slots

    if (stage_next) {                      // rows t0+32 .. t0+63, 8 per wave
        const long g0 = t0 + TILE_T + wv * 8;
        const float* gp = x + g0 * stride + cc0 + lane * 4;
        float* lp = lds0 + ((TPAR + TILE_T + wv * 8) & 63) * BLOCK; // no wrap in +i
        #pragma unroll
        for (int i = 0; i < 8; ++i)
            stage16(gp + (long)i * stride, lp + i * BLOCK);
    }

    float* po = out + t0 * stride + cc0 + tid;
    conv_b<TPAR, 30>(col, taps, acc, po, stride);

    __syncthreads();                       // drains vmcnt: staged rows ready
}

__global__ __launch_bounds__(BLOCK, 2) void lightconv_kernel(
    const float* __restrict__ x,
    const float* __restrict__ w,
    float* __restrict__ out)
{
    __shared__ float ring[RING_ROWS][BLOCK];   // 65536 B

    const int tid    = threadIdx.x;
    const int lane   = tid & 63;
    const int wv     = tid >> 6;
    const int colBlk = blockIdx.x;             // 0..31  (B*C / BLOCK)
    const int tg     = blockIdx.y;             // 0..15  (T / (TPB*TILE_T))
    const int cc0    = colBlk * BLOCK;
    const long stride = (long)B_DIM * C_DIM;
    const long tgbase = (long)tg * (TPB * TILE_T);   // tg*256, ≡0 mod 64

    // ---- prologue: stage rows tgbase-30 .. tgbase+31 (62 rows) ----
    {
        const int r0 = wv * 16;
        const int rn = (wv == 3) ? 14 : 16;
        #pragma unroll
        for (int i = 0; i < 16; ++i) {
            if (i < rn) {
                const long gr = tgbase - PAD_L + r0 + i;
                const int slot = ((int)gr) & 63;         // -30&63 = 34 etc.
                if (gr >= 0) {                           // uniform: only tg==0 pads
                    stage16(x + gr * stride + cc0 + lane * 4, &ring[slot][0]);
                } else {
                    const f32x4 z = {0.f, 0.f, 0.f, 0.f};
                    *(f32x4*)&ring[slot][lane * 4] = z;
                }
            }
        }
    }

    // ---- per-wave redundant softmax -> SGPR taps (no LDS, no extra sync) ----
    // Wave spans exactly one head: h = (colBlk&3)*4 + wv. All lanes compute
    // identical values from broadcast loads; readfirstlane pins them to SGPRs.
    float taps[K_DIM];
    {
        const float* wr = w + (((colBlk & 3) << 2) + wv) * K_DIM;
        float tv[K_DIM];
        float m = -1e30f;
        #pragma unroll
        for (int k = 0; k < K_DIM; ++k) { tv[k] = wr[k]; m = fmaxf(m, tv[k]); }
        float s = 0.f;
        #pragma unroll
        for (int k = 0; k < K_DIM; ++k) { tv[k] = __expf(tv[k] - m); s += tv[k]; }
        const float inv = 1.0f / s;
        #pragma unroll
        for (int k = 0; k < K_DIM; ++k)
            taps[k] = __int_as_float(__builtin_amdgcn_readfirstlane(
                          __float_as_int(tv[k] * inv)));
    }

    __syncthreads();   // prologue stage drained (vmcnt(0) + barrier)

    const float* col = &ring[0][0] + tid;
    float* lds0 = &ring[0][0];
    long t0 = tgbase;
    #pragma unroll 1
    for (int it = 0; it < TPB; ++it, t0 += TILE_T) {
        const bool sn = (it < TPB - 1);
        if (it & 1) iter_body<32>(x, out, col, lds0, taps, t0, wv, lane, cc0, tid, sn);
        else        iter_body< 0>(x, out, col, lds0, taps, t0, wv, lane, cc0, tid, sn);
    }
}

extern "C" void kernel_launch(void* const* d_in, const int* in_sizes, int n_in,
                              void* d_out, int out_size, void* d_ws, size_t ws_size,
                              hipStream_t stream) {
    const float* x = (const float*)d_in[0];    // [T, B, C] fp32
    const float* w = (const float*)d_in[1];    // [H, K]    fp32
    float* out = (float*)d_out;                // [T, B, C] fp32

    dim3 grid((B_DIM * C_DIM) / BLOCK, T_DIM / (TPB * TILE_T));  // (32, 16)
    lightconv_kernel<<<grid, BLOCK, 0, stream>>>(x, w, out);
}